// Round 1
// baseline (6803.979 us; speedup 1.0000x reference)
//
#include <hip/hip_runtime.h>
#include <cstddef>

// Problem constants
#define N_NODES 50000
#define N_EDGES 800000
#define IN_DIM  128
#define EMB     32
#define ED      8
#define NLAYERS 4
#define NB      64
#define OUTD    10
#define EPS_BN  1e-5f

// Edge kernels: 6 edges/thread, grid chosen so all blocks co-resident (no round quantization)
#define EPT   6
#define EGRID 521   // ceil(800000 / (256*6))

// ---------------- helpers ----------------

// acc[c] += v.{x,y,z,w} * w[k..k+3][c]; wk points at 4 consecutive weight rows (row stride EMB).
// wk is wave-uniform -> compiler emits scalar loads (s_load) and v_fmac with SGPR operand.
__device__ __forceinline__ void mac_f4(float acc[EMB], const float4 v, const float* __restrict__ wk) {
#pragma unroll
  for (int c = 0; c < EMB; ++c) acc[c] = fmaf(v.x, wk[c], acc[c]);
#pragma unroll
  for (int c = 0; c < EMB; ++c) acc[c] = fmaf(v.y, wk[EMB + c], acc[c]);
#pragma unroll
  for (int c = 0; c < EMB; ++c) acc[c] = fmaf(v.z, wk[2*EMB + c], acc[c]);
#pragma unroll
  for (int c = 0; c < EMB; ++c) acc[c] = fmaf(v.w, wk[3*EMB + c], acc[c]);
}

// Block-level reduction of per-thread (sum[32], sumsq[32]) -> one atomicAdd per column per block.
// gstats layout: [0..31]=sum, [32..63]=sumsq
__device__ __forceinline__ void block_stats(const float ts[EMB], const float tss[EMB],
                                            float* __restrict__ gstats) {
  __shared__ float sred[256];  // 4 waves x 64
  const int lane = threadIdx.x & 63;
  const int wid  = threadIdx.x >> 6;
#pragma unroll
  for (int c = 0; c < EMB; ++c) {
    float a = ts[c];
    float q = tss[c];
#pragma unroll
    for (int o = 32; o > 0; o >>= 1) {
      a += __shfl_down(a, o, 64);
      q += __shfl_down(q, o, 64);
    }
    if (lane == 0) { sred[wid*64 + c] = a; sred[wid*64 + EMB + c] = q; }
  }
  __syncthreads();
  if (threadIdx.x < 64) {
    float v = sred[threadIdx.x] + sred[64 + threadIdx.x] +
              sred[128 + threadIdx.x] + sred[192 + threadIdx.x];
    atomicAdd(gstats + threadIdx.x, v);
  }
}

// ---------------- kernels ----------------

// h = x @ lin_in_w + lin_in_b   (h row-major [N][32])
__global__ __launch_bounds__(256) void k_lin_in(
    const float* __restrict__ x, const float* __restrict__ w, const float* __restrict__ b,
    float* __restrict__ h)
{
  const int n = blockIdx.x*256 + threadIdx.x;
  if (n >= N_NODES) return;
  float acc[EMB];
#pragma unroll
  for (int c = 0; c < EMB; ++c) acc[c] = b[c];
  const float4* xp = (const float4*)(x + (size_t)n*IN_DIM);
#pragma unroll 4
  for (int q = 0; q < IN_DIM/4; ++q) mac_f4(acc, xp[q], w + q*4*EMB);
  float4* hp = (float4*)(h + (size_t)n*EMB);
#pragma unroll
  for (int q = 0; q < 8; ++q) {
    float4 o; o.x = acc[4*q]; o.y = acc[4*q+1]; o.z = acc[4*q+2]; o.w = acc[4*q+3];
    hp[q] = o;
  }
}

// y1[e] = concat(h[dst], h[src], ea[e]) @ w1 + b1 ; y1 stored COLUMN-major [32][E]; stats accumulated.
__global__ __launch_bounds__(256) void k_msg1(
    const float* __restrict__ h, const int* __restrict__ ei, const float* __restrict__ ea,
    const float* __restrict__ w, const float* __restrict__ b,
    float* __restrict__ y1, float* __restrict__ gstats)
{
  float ts[EMB], tss[EMB];
#pragma unroll
  for (int c = 0; c < EMB; ++c) { ts[c] = 0.f; tss[c] = 0.f; }
  const int base = blockIdx.x*(256*EPT) + threadIdx.x;
  for (int i = 0; i < EPT; ++i) {
    const int e = base + i*256;
    if (e >= N_EDGES) break;
    const int dst = ei[N_EDGES + e];
    const int src = ei[e];
    float acc[EMB];
#pragma unroll
    for (int c = 0; c < EMB; ++c) acc[c] = b[c];
    const float4* hd = (const float4*)(h + (size_t)dst*EMB);
    const float4* hs = (const float4*)(h + (size_t)src*EMB);
    const float4* ep = (const float4*)(ea + (size_t)e*ED);
#pragma unroll
    for (int q = 0; q < 8; ++q) mac_f4(acc, hd[q], w + q*4*EMB);
#pragma unroll
    for (int q = 0; q < 8; ++q) mac_f4(acc, hs[q], w + (EMB + q*4)*EMB);
#pragma unroll
    for (int q = 0; q < 2; ++q) mac_f4(acc, ep[q], w + (2*EMB + q*4)*EMB);
#pragma unroll
    for (int c = 0; c < EMB; ++c) {
      const float v = acc[c];
      y1[(size_t)c*N_EDGES + e] = v;
      ts[c] += v;
      tss[c] = fmaf(v, v, tss[c]);
    }
  }
  block_stats(ts, tss, gstats);
}

// BN finalize: coef[c]=a=g*rsqrt(var+eps), coef[32+c]=be-mu*a. One block, 32 threads.
__global__ void k_bnfin(const float* __restrict__ gstats, const float* __restrict__ g,
                        const float* __restrict__ be, float* __restrict__ coef, float inv_count)
{
  const int c = threadIdx.x;
  const float mu  = gstats[c] * inv_count;
  const float var = gstats[EMB + c] * inv_count - mu*mu;
  const float a = g[c] * rsqrtf(var + EPS_BN);
  coef[c] = a;
  coef[EMB + c] = fmaf(-mu, a, be[c]);
}

// stats pass for msg-linear2: y2 = relu(bn1(y1)) @ w2 + b2 ; only stats, no store.
__global__ __launch_bounds__(256) void k_msg2(
    const float* __restrict__ y1, const float* __restrict__ coef1,
    const float* __restrict__ w, const float* __restrict__ b,
    float* __restrict__ gstats)
{
  float ts[EMB], tss[EMB];
#pragma unroll
  for (int c = 0; c < EMB; ++c) { ts[c] = 0.f; tss[c] = 0.f; }
  const int base = blockIdx.x*(256*EPT) + threadIdx.x;
  for (int i = 0; i < EPT; ++i) {
    const int e = base + i*256;
    if (e >= N_EDGES) break;
    float acc[EMB];
#pragma unroll
    for (int c = 0; c < EMB; ++c) acc[c] = b[c];
#pragma unroll
    for (int k = 0; k < EMB; ++k) {
      float m = y1[(size_t)k*N_EDGES + e];
      m = fmaxf(fmaf(coef1[k], m, coef1[EMB + k]), 0.f);
      const float* wk = w + k*EMB;
#pragma unroll
      for (int c = 0; c < EMB; ++c) acc[c] = fmaf(m, wk[c], acc[c]);
    }
#pragma unroll
    for (int c = 0; c < EMB; ++c) {
      ts[c] += acc[c];
      tss[c] = fmaf(acc[c], acc[c], tss[c]);
    }
  }
  block_stats(ts, tss, gstats);
}

// recompute y2, apply bn2+relu, scatter-add into aggr[dst] (row-major [N][32])
__global__ __launch_bounds__(256) void k_scatter(
    const float* __restrict__ y1, const int* __restrict__ ei,
    const float* __restrict__ coef1, const float* __restrict__ w, const float* __restrict__ b,
    const float* __restrict__ coef2, float* __restrict__ aggr)
{
  const int e = blockIdx.x*256 + threadIdx.x;  // grid = 3125, exact
  if (e >= N_EDGES) return;
  const int dst = ei[N_EDGES + e];
  float acc[EMB];
#pragma unroll
  for (int c = 0; c < EMB; ++c) acc[c] = b[c];
#pragma unroll
  for (int k = 0; k < EMB; ++k) {
    float m = y1[(size_t)k*N_EDGES + e];
    m = fmaxf(fmaf(coef1[k], m, coef1[EMB + k]), 0.f);
    const float* wk = w + k*EMB;
#pragma unroll
    for (int c = 0; c < EMB; ++c) acc[c] = fmaf(m, wk[c], acc[c]);
  }
  float* arow = aggr + (size_t)dst*EMB;
#pragma unroll
  for (int c = 0; c < EMB; ++c) {
    const float m2 = fmaxf(fmaf(coef2[c], acc[c], coef2[EMB + c]), 0.f);
    atomicAdd(arow + c, m2);
  }
}

// z1 = concat(h, aggr) @ upd_w1 + b ; z1 stored column-major [32][N]; stats.
__global__ __launch_bounds__(256) void k_upd1(
    const float* __restrict__ h, const float* __restrict__ aggr,
    const float* __restrict__ w, const float* __restrict__ b,
    float* __restrict__ z1, float* __restrict__ gstats)
{
  const int n = blockIdx.x*256 + threadIdx.x;
  float acc[EMB];
#pragma unroll
  for (int c = 0; c < EMB; ++c) acc[c] = 0.f;
  if (n < N_NODES) {
#pragma unroll
    for (int c = 0; c < EMB; ++c) acc[c] = b[c];
    const float4* hp = (const float4*)(h + (size_t)n*EMB);
    const float4* ap = (const float4*)(aggr + (size_t)n*EMB);
#pragma unroll
    for (int q = 0; q < 8; ++q) mac_f4(acc, hp[q], w + q*4*EMB);
#pragma unroll
    for (int q = 0; q < 8; ++q) mac_f4(acc, ap[q], w + (EMB + q*4)*EMB);
#pragma unroll
    for (int c = 0; c < EMB; ++c) z1[(size_t)c*N_NODES + n] = acc[c];
  }
  float ts[EMB], tss[EMB];
#pragma unroll
  for (int c = 0; c < EMB; ++c) { ts[c] = acc[c]; tss[c] = acc[c]*acc[c]; }
  block_stats(ts, tss, gstats);
}

// z2 = relu(bn(z1)) @ upd_w2 + b ; z2 row-major [N][32]; stats.
__global__ __launch_bounds__(256) void k_upd2(
    const float* __restrict__ z1, const float* __restrict__ coef1,
    const float* __restrict__ w, const float* __restrict__ b,
    float* __restrict__ z2, float* __restrict__ gstats)
{
  const int n = blockIdx.x*256 + threadIdx.x;
  float acc[EMB];
#pragma unroll
  for (int c = 0; c < EMB; ++c) acc[c] = 0.f;
  if (n < N_NODES) {
#pragma unroll
    for (int c = 0; c < EMB; ++c) acc[c] = b[c];
#pragma unroll
    for (int k = 0; k < EMB; ++k) {
      float m = z1[(size_t)k*N_NODES + n];
      m = fmaxf(fmaf(coef1[k], m, coef1[EMB + k]), 0.f);
      const float* wk = w + k*EMB;
#pragma unroll
      for (int c = 0; c < EMB; ++c) acc[c] = fmaf(m, wk[c], acc[c]);
    }
    float4* zp = (float4*)(z2 + (size_t)n*EMB);
#pragma unroll
    for (int q = 0; q < 8; ++q) {
      float4 o; o.x = acc[4*q]; o.y = acc[4*q+1]; o.z = acc[4*q+2]; o.w = acc[4*q+3];
      zp[q] = o;
    }
  }
  float ts[EMB], tss[EMB];
#pragma unroll
  for (int c = 0; c < EMB; ++c) { ts[c] = acc[c]; tss[c] = acc[c]*acc[c]; }
  block_stats(ts, tss, gstats);
}

// h += relu(bn(z2)) elementwise. grid = N*32/256 exact.
__global__ void k_resid(float* __restrict__ h, const float* __restrict__ z2,
                        const float* __restrict__ coef)
{
  const int t = blockIdx.x*256 + threadIdx.x;
  if (t >= N_NODES*EMB) return;
  const int c = t & (EMB-1);
  const float v = fmaf(coef[c], z2[t], coef[EMB + c]);
  h[t] += fmaxf(v, 0.f);
}

// per-graph mean pool (batch sorted -> binary search range) + final linear. One block per graph.
__global__ void k_pool(const float* __restrict__ h, const int* __restrict__ batch,
                       const float* __restrict__ pw, const float* __restrict__ pb,
                       float* __restrict__ out)
{
  __shared__ float sred[256];
  __shared__ float hg[EMB];
  const int b = blockIdx.x;
  int lo = 0, hi = N_NODES;
  while (lo < hi) { int m = (lo + hi) >> 1; if (batch[m] < b) lo = m + 1; else hi = m; }
  const int start = lo;
  hi = N_NODES;
  while (lo < hi) { int m = (lo + hi) >> 1; if (batch[m] < b + 1) lo = m + 1; else hi = m; }
  const int end = lo;

  const int c = threadIdx.x & (EMB-1);
  const int r = threadIdx.x >> 5;  // 0..7
  float s = 0.f;
  for (int n = start + r; n < end; n += 8) s += h[(size_t)n*EMB + c];
  sred[threadIdx.x] = s;
  __syncthreads();
  if (threadIdx.x < EMB) {
    float tot = 0.f;
#pragma unroll
    for (int r2 = 0; r2 < 8; ++r2) tot += sred[r2*EMB + threadIdx.x];
    const float cnt = (float)(end - start);
    hg[threadIdx.x] = tot / fmaxf(cnt, 1.f);
  }
  __syncthreads();
  if (threadIdx.x < OUTD) {
    float acc = pb[threadIdx.x];
#pragma unroll
    for (int cc = 0; cc < EMB; ++cc) acc = fmaf(hg[cc], pw[cc*OUTD + threadIdx.x], acc);
    out[b*OUTD + threadIdx.x] = acc;
  }
}

// ---------------- host ----------------

extern "C" void kernel_launch(void* const* d_in, const int* in_sizes, int n_in,
                              void* d_out, int out_size, void* d_ws, size_t ws_size,
                              hipStream_t stream) {
  const float* x        = (const float*)d_in[0];
  const int*   ei       = (const int*)  d_in[1];
  const float* ea       = (const float*)d_in[2];
  const int*   batch    = (const int*)  d_in[3];
  const float* lin_in_w = (const float*)d_in[4];
  const float* lin_in_b = (const float*)d_in[5];
  const float* msg_w1   = (const float*)d_in[6];
  const float* msg_b1   = (const float*)d_in[7];
  const float* msg_g1   = (const float*)d_in[8];
  const float* msg_be1  = (const float*)d_in[9];
  const float* msg_w2   = (const float*)d_in[10];
  const float* msg_b2   = (const float*)d_in[11];
  const float* msg_g2   = (const float*)d_in[12];
  const float* msg_be2  = (const float*)d_in[13];
  const float* upd_w1   = (const float*)d_in[14];
  const float* upd_b1   = (const float*)d_in[15];
  const float* upd_g1   = (const float*)d_in[16];
  const float* upd_be1  = (const float*)d_in[17];
  const float* upd_w2   = (const float*)d_in[18];
  const float* upd_b2   = (const float*)d_in[19];
  const float* upd_g2   = (const float*)d_in[20];
  const float* upd_be2  = (const float*)d_in[21];
  const float* pred_w   = (const float*)d_in[22];
  const float* pred_b   = (const float*)d_in[23];
  float* out = (float*)d_out;

  // Workspace layout (floats). Total = 32,002,048 floats = 128.01 MB
  float* ws    = (float*)d_ws;
  float* h     = ws;                          // N*32
  float* y1    = h    + (size_t)N_NODES*EMB;  // 32*E column-major
  float* aggr  = y1   + (size_t)EMB*N_EDGES;  // N*32
  float* z1    = aggr + (size_t)N_NODES*EMB;  // 32*N column-major
  float* z2    = z1   + (size_t)N_NODES*EMB;  // N*32
  float* stats = z2   + (size_t)N_NODES*EMB;  // 16 stages x 64
  float* coef  = stats + 16*64;               // 16 stages x 64
  const size_t need_bytes = ((size_t)(coef + 16*64) - (size_t)ws);
  if (ws_size < need_bytes) return;  // cannot run without scratch

  const float invE = 1.0f / (float)N_EDGES;
  const float invN = 1.0f / (float)N_NODES;

  hipMemsetAsync(stats, 0, 16*64*sizeof(float), stream);
  k_lin_in<<<(N_NODES + 255)/256, 256, 0, stream>>>(x, lin_in_w, lin_in_b, h);

  for (int l = 0; l < NLAYERS; ++l) {
    const int st = l*4;
    const float* w1 = msg_w1 + (size_t)l*(2*EMB+ED)*EMB;
    const float* w2 = msg_w2 + (size_t)l*EMB*EMB;
    const float* uw1 = upd_w1 + (size_t)l*(2*EMB)*EMB;
    const float* uw2 = upd_w2 + (size_t)l*EMB*EMB;

    k_msg1<<<EGRID, 256, 0, stream>>>(h, ei, ea, w1, msg_b1 + l*EMB, y1, stats + st*64);
    k_bnfin<<<1, 32, 0, stream>>>(stats + st*64, msg_g1 + l*EMB, msg_be1 + l*EMB,
                                  coef + st*64, invE);
    k_msg2<<<EGRID, 256, 0, stream>>>(y1, coef + st*64, w2, msg_b2 + l*EMB, stats + (st+1)*64);
    k_bnfin<<<1, 32, 0, stream>>>(stats + (st+1)*64, msg_g2 + l*EMB, msg_be2 + l*EMB,
                                  coef + (st+1)*64, invE);
    hipMemsetAsync(aggr, 0, (size_t)N_NODES*EMB*sizeof(float), stream);
    k_scatter<<<N_EDGES/256, 256, 0, stream>>>(y1, ei, coef + st*64, w2, msg_b2 + l*EMB,
                                               coef + (st+1)*64, aggr);
    k_upd1<<<(N_NODES + 255)/256, 256, 0, stream>>>(h, aggr, uw1, upd_b1 + l*EMB,
                                                    z1, stats + (st+2)*64);
    k_bnfin<<<1, 32, 0, stream>>>(stats + (st+2)*64, upd_g1 + l*EMB, upd_be1 + l*EMB,
                                  coef + (st+2)*64, invN);
    k_upd2<<<(N_NODES + 255)/256, 256, 0, stream>>>(z1, coef + (st+2)*64, uw2, upd_b2 + l*EMB,
                                                    z2, stats + (st+3)*64);
    k_bnfin<<<1, 32, 0, stream>>>(stats + (st+3)*64, upd_g2 + l*EMB, upd_be2 + l*EMB,
                                  coef + (st+3)*64, invN);
    k_resid<<<(N_NODES*EMB)/256, 256, 0, stream>>>(h, z2, coef + (st+3)*64);
  }

  k_pool<<<NB, 256, 0, stream>>>(h, batch, pred_w, pred_b, out);
}

// Round 2
// 4239.807 us; speedup vs baseline: 1.6048x; 1.6048x over previous
//
#include <hip/hip_runtime.h>
#include <cstddef>

// Problem constants
#define N_NODES 50000
#define N_EDGES 800000
#define IN_DIM  128
#define EMB     32
#define ED      8
#define NLAYERS 4
#define NB      64
#define OUTD    10
#define EPS_BN  1e-5f

#define EPT1     2
#define MSG1_GRID 1563   // ceil(800000 / (256*2))
#define MSG2_GRID 3125   // 800000/256 exact
#define NODE_GRID 196    // ceil(50000/256)
#define STATS_GRID 1024
#define AGGR_GRID 6250   // 50000/8
#define ELEM_GRID 6250   // 1600000/256

// ---------------- helpers ----------------

__device__ __forceinline__ unsigned short f2bf(float x) {
  union { float f; unsigned u; } v; v.f = x;
  unsigned b = v.u + 0x7FFFu + ((v.u >> 16) & 1u);
  return (unsigned short)(b >> 16);
}
__device__ __forceinline__ float bf2f(unsigned short s) {
  union { unsigned u; float f; } v; v.u = ((unsigned)s) << 16;
  return v.f;
}

// acc[c] += v.{x,y,z,w} * w[k..k+3][c]; wk wave-uniform -> scalar loads + v_fmac.
__device__ __forceinline__ void mac_f4(float acc[EMB], const float4 v, const float* __restrict__ wk) {
#pragma unroll
  for (int c = 0; c < EMB; ++c) acc[c] = fmaf(v.x, wk[c], acc[c]);
#pragma unroll
  for (int c = 0; c < EMB; ++c) acc[c] = fmaf(v.y, wk[EMB + c], acc[c]);
#pragma unroll
  for (int c = 0; c < EMB; ++c) acc[c] = fmaf(v.z, wk[2*EMB + c], acc[c]);
#pragma unroll
  for (int c = 0; c < EMB; ++c) acc[c] = fmaf(v.w, wk[3*EMB + c], acc[c]);
}

// Block reduce (sum[32], sumsq[32]) -> partial[blockIdx*64 + {0..63}]. No atomics.
__device__ __forceinline__ void block_partial(const float ts[EMB], const float tss[EMB],
                                              float* __restrict__ partial) {
  __shared__ float sred[256];
  const int lane = threadIdx.x & 63;
  const int wid  = threadIdx.x >> 6;
#pragma unroll
  for (int c = 0; c < EMB; ++c) {
    float a = ts[c];
    float q = tss[c];
#pragma unroll
    for (int o = 32; o > 0; o >>= 1) {
      a += __shfl_down(a, o, 64);
      q += __shfl_down(q, o, 64);
    }
    if (lane == 0) { sred[wid*64 + c] = a; sred[wid*64 + EMB + c] = q; }
  }
  __syncthreads();
  if (threadIdx.x < 64) {
    partial[(size_t)blockIdx.x*64 + threadIdx.x] =
        sred[threadIdx.x] + sred[64 + threadIdx.x] +
        sred[128 + threadIdx.x] + sred[192 + threadIdx.x];
  }
}

// edge-part of y1: acc = b1 + p[dst] + q[src] + ea[e] @ w1b   (w1b = rows 64..71 of W1)
__device__ __forceinline__ void msg1_acc(float acc[EMB], const float* __restrict__ p,
                                         const float* __restrict__ q, int dst, int src,
                                         const float* __restrict__ ea, int e,
                                         const float* __restrict__ w1b,
                                         const float* __restrict__ b1) {
  const float4* pd = (const float4*)(p + (size_t)dst*EMB);
  const float4* qs = (const float4*)(q + (size_t)src*EMB);
#pragma unroll
  for (int q8 = 0; q8 < 8; ++q8) {
    const float4 a = pd[q8];
    const float4 b = qs[q8];
    acc[4*q8+0] = b1[4*q8+0] + a.x + b.x;
    acc[4*q8+1] = b1[4*q8+1] + a.y + b.y;
    acc[4*q8+2] = b1[4*q8+2] + a.z + b.z;
    acc[4*q8+3] = b1[4*q8+3] + a.w + b.w;
  }
  const float4* ep = (const float4*)(ea + (size_t)e*ED);
  mac_f4(acc, ep[0], w1b);
  mac_f4(acc, ep[1], w1b + 4*EMB);
}

// ---------------- kernels ----------------

// h = x @ lin_in_w + lin_in_b
__global__ __launch_bounds__(256) void k_lin_in(
    const float* __restrict__ x, const float* __restrict__ w, const float* __restrict__ b,
    float* __restrict__ h)
{
  const int n = blockIdx.x*256 + threadIdx.x;
  if (n >= N_NODES) return;
  float acc[EMB];
#pragma unroll
  for (int c = 0; c < EMB; ++c) acc[c] = b[c];
  const float4* xp = (const float4*)(x + (size_t)n*IN_DIM);
#pragma unroll 4
  for (int q = 0; q < IN_DIM/4; ++q) mac_f4(acc, xp[q], w + q*4*EMB);
  float4* hp = (float4*)(h + (size_t)n*EMB);
#pragma unroll
  for (int q = 0; q < 8; ++q) {
    float4 o; o.x = acc[4*q]; o.y = acc[4*q+1]; o.z = acc[4*q+2]; o.w = acc[4*q+3];
    hp[q] = o;
  }
}

// p[n] = h[n] @ W1[0:32], q[n] = h[n] @ W1[32:64]
__global__ __launch_bounds__(256) void k_pq(
    const float* __restrict__ h, const float* __restrict__ w1,
    float* __restrict__ p, float* __restrict__ q)
{
  const int n = blockIdx.x*256 + threadIdx.x;
  if (n >= N_NODES) return;
  float ap[EMB], aq[EMB];
#pragma unroll
  for (int c = 0; c < EMB; ++c) { ap[c] = 0.f; aq[c] = 0.f; }
  const float4* hp = (const float4*)(h + (size_t)n*EMB);
#pragma unroll
  for (int q8 = 0; q8 < 8; ++q8) {
    const float4 v = hp[q8];
    mac_f4(ap, v, w1 + q8*4*EMB);
    mac_f4(aq, v, w1 + (EMB + q8*4)*EMB);
  }
  float4* pp = (float4*)(p + (size_t)n*EMB);
  float4* qp = (float4*)(q + (size_t)n*EMB);
#pragma unroll
  for (int q8 = 0; q8 < 8; ++q8) {
    float4 o1; o1.x = ap[4*q8]; o1.y = ap[4*q8+1]; o1.z = ap[4*q8+2]; o1.w = ap[4*q8+3];
    float4 o2; o2.x = aq[4*q8]; o2.y = aq[4*q8+1]; o2.z = aq[4*q8+2]; o2.w = aq[4*q8+3];
    pp[q8] = o1; qp[q8] = o2;
  }
}

// stats of y1 (no store): y1[e] = p[dst]+q[src]+ea@w1b+b1
__global__ __launch_bounds__(256) void k_msg1(
    const float* __restrict__ p, const float* __restrict__ q,
    const int* __restrict__ ei, const float* __restrict__ ea,
    const float* __restrict__ w1b, const float* __restrict__ b1,
    float* __restrict__ partial)
{
  float ts[EMB], tss[EMB];
#pragma unroll
  for (int c = 0; c < EMB; ++c) { ts[c] = 0.f; tss[c] = 0.f; }
  const int base = blockIdx.x*(256*EPT1) + threadIdx.x;
  for (int i = 0; i < EPT1; ++i) {
    const int e = base + i*256;
    if (e >= N_EDGES) break;
    const int dst = ei[N_EDGES + e];
    const int src = ei[e];
    float acc[EMB];
    msg1_acc(acc, p, q, dst, src, ea, e, w1b, b1);
#pragma unroll
    for (int c = 0; c < EMB; ++c) {
      ts[c] += acc[c];
      tss[c] = fmaf(acc[c], acc[c], tss[c]);
    }
  }
  block_partial(ts, tss, partial);
}

// BN finalize from partials: coef[c]=a, coef[32+c]=be-mu*a
__global__ void k_bnfin(const float* __restrict__ partial, int nblocks,
                        const float* __restrict__ g, const float* __restrict__ be,
                        float* __restrict__ coef, float inv_count)
{
  const int c = threadIdx.x;
  float s = 0.f, ss = 0.f;
  for (int b = 0; b < nblocks; ++b) {
    s  += partial[(size_t)b*64 + c];
    ss += partial[(size_t)b*64 + EMB + c];
  }
  const float mu  = s * inv_count;
  const float var = ss * inv_count - mu*mu;
  const float a = g[c] * rsqrtf(var + EPS_BN);
  coef[c] = a;
  coef[EMB + c] = fmaf(-mu, a, be[c]);
}

// y2_pre = relu(bn1(y1)) @ w2 + b2, stored bf16 row-major [E][32]
__global__ __launch_bounds__(256) void k_msg2(
    const float* __restrict__ p, const float* __restrict__ q,
    const int* __restrict__ ei, const float* __restrict__ ea,
    const float* __restrict__ w1b, const float* __restrict__ b1,
    const float* __restrict__ coef1,
    const float* __restrict__ w2, const float* __restrict__ b2,
    unsigned short* __restrict__ y2)
{
  const int e = blockIdx.x*256 + threadIdx.x;
  if (e >= N_EDGES) return;
  const int dst = ei[N_EDGES + e];
  const int src = ei[e];
  float m[EMB];
  msg1_acc(m, p, q, dst, src, ea, e, w1b, b1);
#pragma unroll
  for (int k = 0; k < EMB; ++k)
    m[k] = fmaxf(fmaf(coef1[k], m[k], coef1[EMB + k]), 0.f);
  float acc[EMB];
#pragma unroll
  for (int c = 0; c < EMB; ++c) acc[c] = b2[c];
#pragma unroll
  for (int k = 0; k < EMB; ++k) {
    const float mk = m[k];
    const float* wk = w2 + k*EMB;
#pragma unroll
    for (int c = 0; c < EMB; ++c) acc[c] = fmaf(mk, wk[c], acc[c]);
  }
  unsigned int u[16];
#pragma unroll
  for (int j = 0; j < 16; ++j)
    u[j] = (unsigned)f2bf(acc[2*j]) | ((unsigned)f2bf(acc[2*j+1]) << 16);
  uint4* dp = (uint4*)(y2 + (size_t)e*EMB);
#pragma unroll
  for (int j = 0; j < 4; ++j) {
    uint4 o; o.x = u[4*j]; o.y = u[4*j+1]; o.z = u[4*j+2]; o.w = u[4*j+3];
    dp[j] = o;
  }
}

// column stats over y2 (bf16). Thread's column fixed: c = threadIdx&31.
__global__ __launch_bounds__(256) void k_stats(
    const unsigned short* __restrict__ y2, float* __restrict__ partial)
{
  const int tid = blockIdx.x*256 + threadIdx.x;
  const int stride = STATS_GRID*256;
  float s = 0.f, ss = 0.f;
  for (size_t i = tid; i < (size_t)N_EDGES*EMB; i += stride) {
    const float v = bf2f(y2[i]);
    s += v;
    ss = fmaf(v, v, ss);
  }
  __shared__ float sred[256];
  sred[threadIdx.x] = s;
  __syncthreads();
  if (threadIdx.x < EMB) {
    float t = 0.f;
#pragma unroll
    for (int m = 0; m < 8; ++m) t += sred[threadIdx.x + EMB*m];
    partial[(size_t)blockIdx.x*64 + threadIdx.x] = t;
  }
  __syncthreads();
  sred[threadIdx.x] = ss;
  __syncthreads();
  if (threadIdx.x < EMB) {
    float t = 0.f;
#pragma unroll
    for (int m = 0; m < 8; ++m) t += sred[threadIdx.x + EMB*m];
    partial[(size_t)blockIdx.x*64 + EMB + threadIdx.x] = t;
  }
}

// ---- CSR build ----
__global__ __launch_bounds__(256) void k_hist(const int* __restrict__ ei, int* __restrict__ cnt) {
  const int e = blockIdx.x*256 + threadIdx.x;
  if (e < N_EDGES) atomicAdd(&cnt[ei[N_EDGES + e]], 1);
}

__global__ __launch_bounds__(1024) void k_scan(const int* __restrict__ cnt, int* __restrict__ row_ptr) {
  __shared__ int part[1024];
  const int t = threadIdx.x;
  const int CH = (N_NODES + 1023) / 1024;  // 49
  const int lo = t*CH, hi = min(lo + CH, N_NODES);
  int s = 0;
  for (int i = lo; i < hi; ++i) s += cnt[i];
  part[t] = s;
  __syncthreads();
  for (int o = 1; o < 1024; o <<= 1) {
    int v = (t >= o) ? part[t - o] : 0;
    __syncthreads();
    part[t] += v;
    __syncthreads();
  }
  int run = (t == 0) ? 0 : part[t-1];
  for (int i = lo; i < hi; ++i) { row_ptr[i] = run; run += cnt[i]; }
  if (t == 0) row_ptr[N_NODES] = N_EDGES;
}

__global__ __launch_bounds__(256) void k_place(const int* __restrict__ ei,
                                               const int* __restrict__ row_ptr,
                                               int* __restrict__ cnt, int* __restrict__ perm) {
  const int e = blockIdx.x*256 + threadIdx.x;
  if (e >= N_EDGES) return;
  const int d = ei[N_EDGES + e];
  const int pos = row_ptr[d] + atomicAdd(&cnt[d], 1);
  perm[pos] = e;
}

// CSR gather: aggr[n][c] = sum over incident edges of relu(bn2(y2[e][c]))
__global__ __launch_bounds__(256) void k_aggr(
    const unsigned short* __restrict__ y2, const int* __restrict__ row_ptr,
    const int* __restrict__ perm, const float* __restrict__ coef2,
    float* __restrict__ aggr)
{
  const int g = threadIdx.x >> 5;
  const int c = threadIdx.x & 31;
  const int n = blockIdx.x*8 + g;
  if (n >= N_NODES) return;
  const float a = coef2[c], b = coef2[EMB + c];
  const int lo = row_ptr[n], hi = row_ptr[n+1];
  float s = 0.f;
  for (int i = lo; i < hi; ++i) {
    const int e = perm[i];
    const float v = bf2f(y2[(size_t)e*EMB + c]);
    s += fmaxf(fmaf(a, v, b), 0.f);
  }
  aggr[(size_t)n*EMB + c] = s;
}

// z1 = concat(h, aggr) @ uw1 + b, written IN PLACE into aggr (own row only). stats.
__global__ __launch_bounds__(256) void k_upd1(
    const float* __restrict__ h, float* __restrict__ aggr,
    const float* __restrict__ w, const float* __restrict__ b,
    float* __restrict__ partial)
{
  const int n = blockIdx.x*256 + threadIdx.x;
  float acc[EMB];
#pragma unroll
  for (int c = 0; c < EMB; ++c) acc[c] = 0.f;
  if (n < N_NODES) {
#pragma unroll
    for (int c = 0; c < EMB; ++c) acc[c] = b[c];
    const float4* hp = (const float4*)(h + (size_t)n*EMB);
    const float4* ap = (const float4*)(aggr + (size_t)n*EMB);
#pragma unroll
    for (int q8 = 0; q8 < 8; ++q8) mac_f4(acc, hp[q8], w + q8*4*EMB);
#pragma unroll
    for (int q8 = 0; q8 < 8; ++q8) mac_f4(acc, ap[q8], w + (EMB + q8*4)*EMB);
    float4* zp = (float4*)(aggr + (size_t)n*EMB);
#pragma unroll
    for (int q8 = 0; q8 < 8; ++q8) {
      float4 o; o.x = acc[4*q8]; o.y = acc[4*q8+1]; o.z = acc[4*q8+2]; o.w = acc[4*q8+3];
      zp[q8] = o;
    }
  }
  float ts[EMB], tss[EMB];
#pragma unroll
  for (int c = 0; c < EMB; ++c) { ts[c] = acc[c]; tss[c] = acc[c]*acc[c]; }
  block_partial(ts, tss, partial);
}

// z2 = relu(bn(z1)) @ uw2 + b, in place (z buffer = aggr). stats.
__global__ __launch_bounds__(256) void k_upd2(
    float* __restrict__ z, const float* __restrict__ coef1,
    const float* __restrict__ w, const float* __restrict__ b,
    float* __restrict__ partial)
{
  const int n = blockIdx.x*256 + threadIdx.x;
  float acc[EMB];
#pragma unroll
  for (int c = 0; c < EMB; ++c) acc[c] = 0.f;
  if (n < N_NODES) {
#pragma unroll
    for (int c = 0; c < EMB; ++c) acc[c] = b[c];
    const float4* zp = (const float4*)(z + (size_t)n*EMB);
#pragma unroll
    for (int q8 = 0; q8 < 8; ++q8) {
      const float4 v = zp[q8];
      float mv[4] = {v.x, v.y, v.z, v.w};
#pragma unroll
      for (int j = 0; j < 4; ++j) {
        const int k = 4*q8 + j;
        const float m = fmaxf(fmaf(coef1[k], mv[j], coef1[EMB + k]), 0.f);
        const float* wk = w + k*EMB;
#pragma unroll
        for (int c = 0; c < EMB; ++c) acc[c] = fmaf(m, wk[c], acc[c]);
      }
    }
    float4* op = (float4*)(z + (size_t)n*EMB);
#pragma unroll
    for (int q8 = 0; q8 < 8; ++q8) {
      float4 o; o.x = acc[4*q8]; o.y = acc[4*q8+1]; o.z = acc[4*q8+2]; o.w = acc[4*q8+3];
      op[q8] = o;
    }
  }
  float ts[EMB], tss[EMB];
#pragma unroll
  for (int c = 0; c < EMB; ++c) { ts[c] = acc[c]; tss[c] = acc[c]*acc[c]; }
  block_partial(ts, tss, partial);
}

// h += relu(bn(z2))
__global__ __launch_bounds__(256) void k_resid(
    float* __restrict__ h, const float* __restrict__ z, const float* __restrict__ coef)
{
  const int t = blockIdx.x*256 + threadIdx.x;
  const int c = t & (EMB-1);
  const float v = fmaf(coef[c], z[t], coef[EMB + c]);
  h[t] += fmaxf(v, 0.f);
}

// per-graph mean pool + final linear
__global__ void k_pool(const float* __restrict__ h, const int* __restrict__ batch,
                       const float* __restrict__ pw, const float* __restrict__ pb,
                       float* __restrict__ out)
{
  __shared__ float sred[256];
  __shared__ float hg[EMB];
  const int b = blockIdx.x;
  int lo = 0, hi = N_NODES;
  while (lo < hi) { int m = (lo + hi) >> 1; if (batch[m] < b) lo = m + 1; else hi = m; }
  const int start = lo;
  hi = N_NODES;
  while (lo < hi) { int m = (lo + hi) >> 1; if (batch[m] < b + 1) lo = m + 1; else hi = m; }
  const int end = lo;

  const int c = threadIdx.x & (EMB-1);
  const int r = threadIdx.x >> 5;
  float s = 0.f;
  for (int n = start + r; n < end; n += 8) s += h[(size_t)n*EMB + c];
  sred[threadIdx.x] = s;
  __syncthreads();
  if (threadIdx.x < EMB) {
    float tot = 0.f;
#pragma unroll
    for (int r2 = 0; r2 < 8; ++r2) tot += sred[r2*EMB + threadIdx.x];
    const float cnt = (float)(end - start);
    hg[threadIdx.x] = tot / fmaxf(cnt, 1.f);
  }
  __syncthreads();
  if (threadIdx.x < OUTD) {
    float acc = pb[threadIdx.x];
#pragma unroll
    for (int cc = 0; cc < EMB; ++cc) acc = fmaf(hg[cc], pw[cc*OUTD + threadIdx.x], acc);
    out[b*OUTD + threadIdx.x] = acc;
  }
}

// ---------------- host ----------------

extern "C" void kernel_launch(void* const* d_in, const int* in_sizes, int n_in,
                              void* d_out, int out_size, void* d_ws, size_t ws_size,
                              hipStream_t stream) {
  const float* x        = (const float*)d_in[0];
  const int*   ei       = (const int*)  d_in[1];
  const float* ea       = (const float*)d_in[2];
  const int*   batch    = (const int*)  d_in[3];
  const float* lin_in_w = (const float*)d_in[4];
  const float* lin_in_b = (const float*)d_in[5];
  const float* msg_w1   = (const float*)d_in[6];
  const float* msg_b1   = (const float*)d_in[7];
  const float* msg_g1   = (const float*)d_in[8];
  const float* msg_be1  = (const float*)d_in[9];
  const float* msg_w2   = (const float*)d_in[10];
  const float* msg_b2   = (const float*)d_in[11];
  const float* msg_g2   = (const float*)d_in[12];
  const float* msg_be2  = (const float*)d_in[13];
  const float* upd_w1   = (const float*)d_in[14];
  const float* upd_b1   = (const float*)d_in[15];
  const float* upd_g1   = (const float*)d_in[16];
  const float* upd_be1  = (const float*)d_in[17];
  const float* upd_w2   = (const float*)d_in[18];
  const float* upd_b2   = (const float*)d_in[19];
  const float* upd_g2   = (const float*)d_in[20];
  const float* upd_be2  = (const float*)d_in[21];
  const float* pred_w   = (const float*)d_in[22];
  const float* pred_b   = (const float*)d_in[23];
  float* out = (float*)d_out;

  // Workspace layout (~81 MB, well under the 128 MB known-good from round 1)
  char* wsb = (char*)d_ws;
  unsigned short* y2 = (unsigned short*)wsb;            // E*32 bf16 = 51.2 MB
  float* h       = (float*)(wsb + (size_t)N_EDGES*EMB*2);
  float* p       = h    + (size_t)N_NODES*EMB;
  float* q       = p    + (size_t)N_NODES*EMB;
  float* aggr    = q    + (size_t)N_NODES*EMB;          // also z1/z2 in place
  float* partial = aggr + (size_t)N_NODES*EMB;          // 2048 rows x 64
  float* coef    = partial + (size_t)2048*64;           // 16 stages x 64
  int*   perm    = (int*)(coef + 16*64);
  int*   cnt     = perm + N_EDGES;
  int*   row_ptr = cnt + N_NODES;
  const size_t need = ((size_t)((char*)(row_ptr + N_NODES + 1) - wsb));
  if (ws_size < need) return;

  const float invE = 1.0f / (float)N_EDGES;
  const float invN = 1.0f / (float)N_NODES;

  // input projection + CSR build (once per call)
  k_lin_in<<<NODE_GRID, 256, 0, stream>>>(x, lin_in_w, lin_in_b, h);
  hipMemsetAsync(cnt, 0, N_NODES*sizeof(int), stream);
  k_hist<<<MSG2_GRID, 256, 0, stream>>>(ei, cnt);
  k_scan<<<1, 1024, 0, stream>>>(cnt, row_ptr);
  hipMemsetAsync(cnt, 0, N_NODES*sizeof(int), stream);
  k_place<<<MSG2_GRID, 256, 0, stream>>>(ei, row_ptr, cnt, perm);

  for (int l = 0; l < NLAYERS; ++l) {
    const int st = l*4;
    const float* w1  = msg_w1 + (size_t)l*(2*EMB+ED)*EMB;
    const float* w1b = w1 + (size_t)2*EMB*EMB;  // ea rows
    const float* w2  = msg_w2 + (size_t)l*EMB*EMB;
    const float* uw1 = upd_w1 + (size_t)l*(2*EMB)*EMB;
    const float* uw2 = upd_w2 + (size_t)l*EMB*EMB;

    k_pq<<<NODE_GRID, 256, 0, stream>>>(h, w1, p, q);
    k_msg1<<<MSG1_GRID, 256, 0, stream>>>(p, q, ei, ea, w1b, msg_b1 + l*EMB, partial);
    k_bnfin<<<1, 32, 0, stream>>>(partial, MSG1_GRID, msg_g1 + l*EMB, msg_be1 + l*EMB,
                                  coef + st*64, invE);
    k_msg2<<<MSG2_GRID, 256, 0, stream>>>(p, q, ei, ea, w1b, msg_b1 + l*EMB,
                                          coef + st*64, w2, msg_b2 + l*EMB, y2);
    k_stats<<<STATS_GRID, 256, 0, stream>>>(y2, partial);
    k_bnfin<<<1, 32, 0, stream>>>(partial, STATS_GRID, msg_g2 + l*EMB, msg_be2 + l*EMB,
                                  coef + (st+1)*64, invE);
    k_aggr<<<AGGR_GRID, 256, 0, stream>>>(y2, row_ptr, perm, coef + (st+1)*64, aggr);
    k_upd1<<<NODE_GRID, 256, 0, stream>>>(h, aggr, uw1, upd_b1 + l*EMB, partial);
    k_bnfin<<<1, 32, 0, stream>>>(partial, NODE_GRID, upd_g1 + l*EMB, upd_be1 + l*EMB,
                                  coef + (st+2)*64, invN);
    k_upd2<<<NODE_GRID, 256, 0, stream>>>(aggr, coef + (st+2)*64, uw2, upd_b2 + l*EMB, partial);
    k_bnfin<<<1, 32, 0, stream>>>(partial, NODE_GRID, upd_g2 + l*EMB, upd_be2 + l*EMB,
                                  coef + (st+3)*64, invN);
    k_resid<<<ELEM_GRID, 256, 0, stream>>>(h, aggr, coef + (st+3)*64);
  }

  k_pool<<<NB, 256, 0, stream>>>(h, batch, pred_w, pred_b, out);
}

// Round 3
// 1810.141 us; speedup vs baseline: 3.7588x; 2.3423x over previous
//
#include <hip/hip_runtime.h>
#include <cstddef>

// Problem constants
#define N_NODES 50000
#define N_EDGES 800000
#define IN_DIM  128
#define EMB     32
#define ED      8
#define NLAYERS 4
#define NB      64
#define OUTD    10
#define EPS_BN  1e-5f

#define EPT1     2
#define MSG1_GRID 1563   // ceil(800000 / (256*2))
#define MSG2_GRID 3125   // 800000/256 exact
#define NODE_GRID 196    // ceil(50000/256)
#define AGGR_GRID 6250   // 50000/8
#define ELEM_GRID 6250   // 1600000/256

// ---------------- helpers ----------------

__device__ __forceinline__ unsigned short f2bf(float x) {
  union { float f; unsigned u; } v; v.f = x;
  unsigned b = v.u + 0x7FFFu + ((v.u >> 16) & 1u);
  return (unsigned short)(b >> 16);
}
__device__ __forceinline__ float bf2f(unsigned short s) {
  union { unsigned u; float f; } v; v.u = ((unsigned)s) << 16;
  return v.f;
}

// acc[c] += v.{x,y,z,w} * w[k..k+3][c]; wk wave-uniform -> scalar loads + v_fmac.
__device__ __forceinline__ void mac_f4(float acc[EMB], const float4 v, const float* __restrict__ wk) {
#pragma unroll
  for (int c = 0; c < EMB; ++c) acc[c] = fmaf(v.x, wk[c], acc[c]);
#pragma unroll
  for (int c = 0; c < EMB; ++c) acc[c] = fmaf(v.y, wk[EMB + c], acc[c]);
#pragma unroll
  for (int c = 0; c < EMB; ++c) acc[c] = fmaf(v.z, wk[2*EMB + c], acc[c]);
#pragma unroll
  for (int c = 0; c < EMB; ++c) acc[c] = fmaf(v.w, wk[3*EMB + c], acc[c]);
}

// Block reduce (sum[32], sumsq[32]) -> partial[blockIdx*64 + {0..63}]. No atomics.
__device__ __forceinline__ void block_partial(const float ts[EMB], const float tss[EMB],
                                              float* __restrict__ partial) {
  __shared__ float sred[256];
  const int lane = threadIdx.x & 63;
  const int wid  = threadIdx.x >> 6;
#pragma unroll
  for (int c = 0; c < EMB; ++c) {
    float a = ts[c];
    float q = tss[c];
#pragma unroll
    for (int o = 32; o > 0; o >>= 1) {
      a += __shfl_down(a, o, 64);
      q += __shfl_down(q, o, 64);
    }
    if (lane == 0) { sred[wid*64 + c] = a; sred[wid*64 + EMB + c] = q; }
  }
  __syncthreads();
  if (threadIdx.x < 64) {
    partial[(size_t)blockIdx.x*64 + threadIdx.x] =
        sred[threadIdx.x] + sred[64 + threadIdx.x] +
        sred[128 + threadIdx.x] + sred[192 + threadIdx.x];
  }
}

// edge-part of y1: acc = b1 + p[dst] + q[src] + ea[e] @ w1b   (w1b = rows 64..71 of W1)
__device__ __forceinline__ void msg1_acc(float acc[EMB], const float* __restrict__ p,
                                         const float* __restrict__ q, int dst, int src,
                                         const float* __restrict__ ea, int e,
                                         const float* __restrict__ w1b,
                                         const float* __restrict__ b1) {
  const float4* pd = (const float4*)(p + (size_t)dst*EMB);
  const float4* qs = (const float4*)(q + (size_t)src*EMB);
#pragma unroll
  for (int q8 = 0; q8 < 8; ++q8) {
    const float4 a = pd[q8];
    const float4 b = qs[q8];
    acc[4*q8+0] = b1[4*q8+0] + a.x + b.x;
    acc[4*q8+1] = b1[4*q8+1] + a.y + b.y;
    acc[4*q8+2] = b1[4*q8+2] + a.z + b.z;
    acc[4*q8+3] = b1[4*q8+3] + a.w + b.w;
  }
  const float4* ep = (const float4*)(ea + (size_t)e*ED);
  mac_f4(acc, ep[0], w1b);
  mac_f4(acc, ep[1], w1b + 4*EMB);
}

// ---------------- kernels ----------------

// h = x @ lin_in_w + lin_in_b
__global__ __launch_bounds__(256) void k_lin_in(
    const float* __restrict__ x, const float* __restrict__ w, const float* __restrict__ b,
    float* __restrict__ h)
{
  const int n = blockIdx.x*256 + threadIdx.x;
  if (n >= N_NODES) return;
  float acc[EMB];
#pragma unroll
  for (int c = 0; c < EMB; ++c) acc[c] = b[c];
  const float4* xp = (const float4*)(x + (size_t)n*IN_DIM);
#pragma unroll 4
  for (int q = 0; q < IN_DIM/4; ++q) mac_f4(acc, xp[q], w + q*4*EMB);
  float4* hp = (float4*)(h + (size_t)n*EMB);
#pragma unroll
  for (int q = 0; q < 8; ++q) {
    float4 o; o.x = acc[4*q]; o.y = acc[4*q+1]; o.z = acc[4*q+2]; o.w = acc[4*q+3];
    hp[q] = o;
  }
}

// p[n] = h[n] @ W1[0:32], q[n] = h[n] @ W1[32:64]
__global__ __launch_bounds__(256) void k_pq(
    const float* __restrict__ h, const float* __restrict__ w1,
    float* __restrict__ p, float* __restrict__ q)
{
  const int n = blockIdx.x*256 + threadIdx.x;
  if (n >= N_NODES) return;
  float ap[EMB], aq[EMB];
#pragma unroll
  for (int c = 0; c < EMB; ++c) { ap[c] = 0.f; aq[c] = 0.f; }
  const float4* hp = (const float4*)(h + (size_t)n*EMB);
#pragma unroll
  for (int q8 = 0; q8 < 8; ++q8) {
    const float4 v = hp[q8];
    mac_f4(ap, v, w1 + q8*4*EMB);
    mac_f4(aq, v, w1 + (EMB + q8*4)*EMB);
  }
  float4* pp = (float4*)(p + (size_t)n*EMB);
  float4* qp = (float4*)(q + (size_t)n*EMB);
#pragma unroll
  for (int q8 = 0; q8 < 8; ++q8) {
    float4 o1; o1.x = ap[4*q8]; o1.y = ap[4*q8+1]; o1.z = ap[4*q8+2]; o1.w = ap[4*q8+3];
    float4 o2; o2.x = aq[4*q8]; o2.y = aq[4*q8+1]; o2.z = aq[4*q8+2]; o2.w = aq[4*q8+3];
    pp[q8] = o1; qp[q8] = o2;
  }
}

// stats of y1 (no store): y1[e] = p[dst]+q[src]+ea@w1b+b1
__global__ __launch_bounds__(256) void k_msg1(
    const float* __restrict__ p, const float* __restrict__ q,
    const int* __restrict__ ei, const float* __restrict__ ea,
    const float* __restrict__ w1b, const float* __restrict__ b1,
    float* __restrict__ partial)
{
  float ts[EMB], tss[EMB];
#pragma unroll
  for (int c = 0; c < EMB; ++c) { ts[c] = 0.f; tss[c] = 0.f; }
  const int base = blockIdx.x*(256*EPT1) + threadIdx.x;
  for (int i = 0; i < EPT1; ++i) {
    const int e = base + i*256;
    if (e >= N_EDGES) break;
    const int dst = ei[N_EDGES + e];
    const int src = ei[e];
    float acc[EMB];
    msg1_acc(acc, p, q, dst, src, ea, e, w1b, b1);
#pragma unroll
    for (int c = 0; c < EMB; ++c) {
      ts[c] += acc[c];
      tss[c] = fmaf(acc[c], acc[c], tss[c]);
    }
  }
  block_partial(ts, tss, partial);
}

// BN finalize from partials, PARALLEL: 1024 threads, 16-way row split + LDS tree.
// coef[c]=a, coef[32+c]=be-mu*a
__global__ __launch_bounds__(1024) void k_bnfin(
    const float* __restrict__ partial, int nblocks,
    const float* __restrict__ g, const float* __restrict__ be,
    float* __restrict__ coef, float inv_count)
{
  __shared__ float sred[1024];
  __shared__ float tot[64];
  const int c = threadIdx.x & 63;   // stat index 0..63
  const int r = threadIdx.x >> 6;   // 0..15
  float s = 0.f;
  for (int b = r; b < nblocks; b += 16) s += partial[(size_t)b*64 + c];
  sred[threadIdx.x] = s;
  __syncthreads();
  if (threadIdx.x < 64) {
    float t = 0.f;
#pragma unroll
    for (int m = 0; m < 16; ++m) t += sred[m*64 + threadIdx.x];
    tot[threadIdx.x] = t;
  }
  __syncthreads();
  if (threadIdx.x < EMB) {
    const float mu  = tot[threadIdx.x] * inv_count;
    const float var = tot[EMB + threadIdx.x] * inv_count - mu*mu;
    const float a = g[threadIdx.x] * rsqrtf(var + EPS_BN);
    coef[threadIdx.x] = a;
    coef[EMB + threadIdx.x] = fmaf(-mu, a, be[threadIdx.x]);
  }
}

// y2_pre = relu(bn1(y1)) @ w2 + b2, stored bf16 row-major [E][32]; stats fused (block partials).
__global__ __launch_bounds__(256) void k_msg2(
    const float* __restrict__ p, const float* __restrict__ q,
    const int* __restrict__ ei, const float* __restrict__ ea,
    const float* __restrict__ w1b, const float* __restrict__ b1,
    const float* __restrict__ coef1,
    const float* __restrict__ w2, const float* __restrict__ b2,
    unsigned short* __restrict__ y2, float* __restrict__ partial)
{
  const int e = blockIdx.x*256 + threadIdx.x;
  const int dst = ei[N_EDGES + e];
  const int src = ei[e];
  float m[EMB];
  msg1_acc(m, p, q, dst, src, ea, e, w1b, b1);
#pragma unroll
  for (int k = 0; k < EMB; ++k)
    m[k] = fmaxf(fmaf(coef1[k], m[k], coef1[EMB + k]), 0.f);
  float acc[EMB];
#pragma unroll
  for (int c = 0; c < EMB; ++c) acc[c] = b2[c];
#pragma unroll
  for (int k = 0; k < EMB; ++k) {
    const float mk = m[k];
    const float* wk = w2 + k*EMB;
#pragma unroll
    for (int c = 0; c < EMB; ++c) acc[c] = fmaf(mk, wk[c], acc[c]);
  }
  // store bf16 (quantize FIRST, take stats of the quantized values so BN stats
  // match exactly what k_aggr will read)
  unsigned short us[EMB];
#pragma unroll
  for (int c = 0; c < EMB; ++c) us[c] = f2bf(acc[c]);
  unsigned int u[16];
#pragma unroll
  for (int j = 0; j < 16; ++j)
    u[j] = (unsigned)us[2*j] | ((unsigned)us[2*j+1] << 16);
  uint4* dp = (uint4*)(y2 + (size_t)e*EMB);
#pragma unroll
  for (int j = 0; j < 4; ++j) {
    uint4 o; o.x = u[4*j]; o.y = u[4*j+1]; o.z = u[4*j+2]; o.w = u[4*j+3];
    dp[j] = o;
  }
  float ts[EMB], tss[EMB];
#pragma unroll
  for (int c = 0; c < EMB; ++c) {
    const float v = bf2f(us[c]);
    ts[c] = v;
    tss[c] = v*v;
  }
  block_partial(ts, tss, partial);
}

// ---- CSR build ----
__global__ __launch_bounds__(256) void k_hist(const int* __restrict__ ei, int* __restrict__ cnt) {
  const int e = blockIdx.x*256 + threadIdx.x;
  if (e < N_EDGES) atomicAdd(&cnt[ei[N_EDGES + e]], 1);
}

__global__ __launch_bounds__(1024) void k_scan(const int* __restrict__ cnt, int* __restrict__ row_ptr) {
  __shared__ int part[1024];
  const int t = threadIdx.x;
  const int CH = (N_NODES + 1023) / 1024;  // 49
  const int lo = t*CH, hi = min(lo + CH, N_NODES);
  int s = 0;
  for (int i = lo; i < hi; ++i) s += cnt[i];
  part[t] = s;
  __syncthreads();
  for (int o = 1; o < 1024; o <<= 1) {
    int v = (t >= o) ? part[t - o] : 0;
    __syncthreads();
    part[t] += v;
    __syncthreads();
  }
  int run = (t == 0) ? 0 : part[t-1];
  for (int i = lo; i < hi; ++i) { row_ptr[i] = run; run += cnt[i]; }
  if (t == 0) row_ptr[N_NODES] = N_EDGES;
}

__global__ __launch_bounds__(256) void k_place(const int* __restrict__ ei,
                                               const int* __restrict__ row_ptr,
                                               int* __restrict__ cnt, int* __restrict__ perm) {
  const int e = blockIdx.x*256 + threadIdx.x;
  if (e >= N_EDGES) return;
  const int d = ei[N_EDGES + e];
  const int pos = row_ptr[d] + atomicAdd(&cnt[d], 1);
  perm[pos] = e;
}

// CSR gather: aggr[n][c] = sum over incident edges of relu(bn2(y2[e][c]))
__global__ __launch_bounds__(256) void k_aggr(
    const unsigned short* __restrict__ y2, const int* __restrict__ row_ptr,
    const int* __restrict__ perm, const float* __restrict__ coef2,
    float* __restrict__ aggr)
{
  const int g = threadIdx.x >> 5;
  const int c = threadIdx.x & 31;
  const int n = blockIdx.x*8 + g;
  if (n >= N_NODES) return;
  const float a = coef2[c], b = coef2[EMB + c];
  const int lo = row_ptr[n], hi = row_ptr[n+1];
  float s = 0.f;
  for (int i = lo; i < hi; ++i) {
    const int e = perm[i];
    const float v = bf2f(y2[(size_t)e*EMB + c]);
    s += fmaxf(fmaf(a, v, b), 0.f);
  }
  aggr[(size_t)n*EMB + c] = s;
}

// z1 = concat(h, aggr) @ uw1 + b, written IN PLACE into aggr (own row only). stats.
__global__ __launch_bounds__(256) void k_upd1(
    const float* __restrict__ h, float* __restrict__ aggr,
    const float* __restrict__ w, const float* __restrict__ b,
    float* __restrict__ partial)
{
  const int n = blockIdx.x*256 + threadIdx.x;
  float acc[EMB];
#pragma unroll
  for (int c = 0; c < EMB; ++c) acc[c] = 0.f;
  if (n < N_NODES) {
#pragma unroll
    for (int c = 0; c < EMB; ++c) acc[c] = b[c];
    const float4* hp = (const float4*)(h + (size_t)n*EMB);
    const float4* ap = (const float4*)(aggr + (size_t)n*EMB);
#pragma unroll
    for (int q8 = 0; q8 < 8; ++q8) mac_f4(acc, hp[q8], w + q8*4*EMB);
#pragma unroll
    for (int q8 = 0; q8 < 8; ++q8) mac_f4(acc, ap[q8], w + (EMB + q8*4)*EMB);
    float4* zp = (float4*)(aggr + (size_t)n*EMB);
#pragma unroll
    for (int q8 = 0; q8 < 8; ++q8) {
      float4 o; o.x = acc[4*q8]; o.y = acc[4*q8+1]; o.z = acc[4*q8+2]; o.w = acc[4*q8+3];
      zp[q8] = o;
    }
  }
  float ts[EMB], tss[EMB];
#pragma unroll
  for (int c = 0; c < EMB; ++c) { ts[c] = acc[c]; tss[c] = acc[c]*acc[c]; }
  block_partial(ts, tss, partial);
}

// z2 = relu(bn(z1)) @ uw2 + b, in place (z buffer = aggr). stats.
__global__ __launch_bounds__(256) void k_upd2(
    float* __restrict__ z, const float* __restrict__ coef1,
    const float* __restrict__ w, const float* __restrict__ b,
    float* __restrict__ partial)
{
  const int n = blockIdx.x*256 + threadIdx.x;
  float acc[EMB];
#pragma unroll
  for (int c = 0; c < EMB; ++c) acc[c] = 0.f;
  if (n < N_NODES) {
#pragma unroll
    for (int c = 0; c < EMB; ++c) acc[c] = b[c];
    const float4* zp = (const float4*)(z + (size_t)n*EMB);
#pragma unroll
    for (int q8 = 0; q8 < 8; ++q8) {
      const float4 v = zp[q8];
      float mv[4] = {v.x, v.y, v.z, v.w};
#pragma unroll
      for (int j = 0; j < 4; ++j) {
        const int k = 4*q8 + j;
        const float m = fmaxf(fmaf(coef1[k], mv[j], coef1[EMB + k]), 0.f);
        const float* wk = w + k*EMB;
#pragma unroll
        for (int c = 0; c < EMB; ++c) acc[c] = fmaf(m, wk[c], acc[c]);
      }
    }
    float4* op = (float4*)(z + (size_t)n*EMB);
#pragma unroll
    for (int q8 = 0; q8 < 8; ++q8) {
      float4 o; o.x = acc[4*q8]; o.y = acc[4*q8+1]; o.z = acc[4*q8+2]; o.w = acc[4*q8+3];
      op[q8] = o;
    }
  }
  float ts[EMB], tss[EMB];
#pragma unroll
  for (int c = 0; c < EMB; ++c) { ts[c] = acc[c]; tss[c] = acc[c]*acc[c]; }
  block_partial(ts, tss, partial);
}

// h += relu(bn(z2))
__global__ __launch_bounds__(256) void k_resid(
    float* __restrict__ h, const float* __restrict__ z, const float* __restrict__ coef)
{
  const int t = blockIdx.x*256 + threadIdx.x;
  const int c = t & (EMB-1);
  const float v = fmaf(coef[c], z[t], coef[EMB + c]);
  h[t] += fmaxf(v, 0.f);
}

// per-graph mean pool + final linear
__global__ void k_pool(const float* __restrict__ h, const int* __restrict__ batch,
                       const float* __restrict__ pw, const float* __restrict__ pb,
                       float* __restrict__ out)
{
  __shared__ float sred[256];
  __shared__ float hg[EMB];
  const int b = blockIdx.x;
  int lo = 0, hi = N_NODES;
  while (lo < hi) { int m = (lo + hi) >> 1; if (batch[m] < b) lo = m + 1; else hi = m; }
  const int start = lo;
  hi = N_NODES;
  while (lo < hi) { int m = (lo + hi) >> 1; if (batch[m] < b + 1) lo = m + 1; else hi = m; }
  const int end = lo;

  const int c = threadIdx.x & (EMB-1);
  const int r = threadIdx.x >> 5;
  float s = 0.f;
  for (int n = start + r; n < end; n += 8) s += h[(size_t)n*EMB + c];
  sred[threadIdx.x] = s;
  __syncthreads();
  if (threadIdx.x < EMB) {
    float tot = 0.f;
#pragma unroll
    for (int r2 = 0; r2 < 8; ++r2) tot += sred[r2*EMB + threadIdx.x];
    const float cnt = (float)(end - start);
    hg[threadIdx.x] = tot / fmaxf(cnt, 1.f);
  }
  __syncthreads();
  if (threadIdx.x < OUTD) {
    float acc = pb[threadIdx.x];
#pragma unroll
    for (int cc = 0; cc < EMB; ++cc) acc = fmaf(hg[cc], pw[cc*OUTD + threadIdx.x], acc);
    out[b*OUTD + threadIdx.x] = acc;
  }
}

// ---------------- host ----------------

extern "C" void kernel_launch(void* const* d_in, const int* in_sizes, int n_in,
                              void* d_out, int out_size, void* d_ws, size_t ws_size,
                              hipStream_t stream) {
  const float* x        = (const float*)d_in[0];
  const int*   ei       = (const int*)  d_in[1];
  const float* ea       = (const float*)d_in[2];
  const int*   batch    = (const int*)  d_in[3];
  const float* lin_in_w = (const float*)d_in[4];
  const float* lin_in_b = (const float*)d_in[5];
  const float* msg_w1   = (const float*)d_in[6];
  const float* msg_b1   = (const float*)d_in[7];
  const float* msg_g1   = (const float*)d_in[8];
  const float* msg_be1  = (const float*)d_in[9];
  const float* msg_w2   = (const float*)d_in[10];
  const float* msg_b2   = (const float*)d_in[11];
  const float* msg_g2   = (const float*)d_in[12];
  const float* msg_be2  = (const float*)d_in[13];
  const float* upd_w1   = (const float*)d_in[14];
  const float* upd_b1   = (const float*)d_in[15];
  const float* upd_g1   = (const float*)d_in[16];
  const float* upd_be1  = (const float*)d_in[17];
  const float* upd_w2   = (const float*)d_in[18];
  const float* upd_b2   = (const float*)d_in[19];
  const float* upd_g2   = (const float*)d_in[20];
  const float* upd_be2  = (const float*)d_in[21];
  const float* pred_w   = (const float*)d_in[22];
  const float* pred_b   = (const float*)d_in[23];
  float* out = (float*)d_out;

  // Workspace layout (~82 MB)
  char* wsb = (char*)d_ws;
  unsigned short* y2 = (unsigned short*)wsb;            // E*32 bf16 = 51.2 MB
  float* h       = (float*)(wsb + (size_t)N_EDGES*EMB*2);
  float* p       = h    + (size_t)N_NODES*EMB;
  float* q       = p    + (size_t)N_NODES*EMB;
  float* aggr    = q    + (size_t)N_NODES*EMB;          // also z1/z2 in place
  float* partial = aggr + (size_t)N_NODES*EMB;          // 3200 rows x 64
  float* coef    = partial + (size_t)3200*64;           // 16 stages x 64
  int*   perm    = (int*)(coef + 16*64);
  int*   cnt     = perm + N_EDGES;
  int*   row_ptr = cnt + N_NODES;
  const size_t need = ((size_t)((char*)(row_ptr + N_NODES + 1) - wsb));
  if (ws_size < need) return;

  const float invE = 1.0f / (float)N_EDGES;
  const float invN = 1.0f / (float)N_NODES;

  // input projection + CSR build (once per call)
  k_lin_in<<<NODE_GRID, 256, 0, stream>>>(x, lin_in_w, lin_in_b, h);
  hipMemsetAsync(cnt, 0, N_NODES*sizeof(int), stream);
  k_hist<<<MSG2_GRID, 256, 0, stream>>>(ei, cnt);
  k_scan<<<1, 1024, 0, stream>>>(cnt, row_ptr);
  hipMemsetAsync(cnt, 0, N_NODES*sizeof(int), stream);
  k_place<<<MSG2_GRID, 256, 0, stream>>>(ei, row_ptr, cnt, perm);

  for (int l = 0; l < NLAYERS; ++l) {
    const int st = l*4;
    const float* w1  = msg_w1 + (size_t)l*(2*EMB+ED)*EMB;
    const float* w1b = w1 + (size_t)2*EMB*EMB;  // ea rows
    const float* w2  = msg_w2 + (size_t)l*EMB*EMB;
    const float* uw1 = upd_w1 + (size_t)l*(2*EMB)*EMB;
    const float* uw2 = upd_w2 + (size_t)l*EMB*EMB;

    k_pq<<<NODE_GRID, 256, 0, stream>>>(h, w1, p, q);
    k_msg1<<<MSG1_GRID, 256, 0, stream>>>(p, q, ei, ea, w1b, msg_b1 + l*EMB, partial);
    k_bnfin<<<1, 1024, 0, stream>>>(partial, MSG1_GRID, msg_g1 + l*EMB, msg_be1 + l*EMB,
                                    coef + st*64, invE);
    k_msg2<<<MSG2_GRID, 256, 0, stream>>>(p, q, ei, ea, w1b, msg_b1 + l*EMB,
                                          coef + st*64, w2, msg_b2 + l*EMB, y2, partial);
    k_bnfin<<<1, 1024, 0, stream>>>(partial, MSG2_GRID, msg_g2 + l*EMB, msg_be2 + l*EMB,
                                    coef + (st+1)*64, invE);
    k_aggr<<<AGGR_GRID, 256, 0, stream>>>(y2, row_ptr, perm, coef + (st+1)*64, aggr);
    k_upd1<<<NODE_GRID, 256, 0, stream>>>(h, aggr, uw1, upd_b1 + l*EMB, partial);
    k_bnfin<<<1, 1024, 0, stream>>>(partial, NODE_GRID, upd_g1 + l*EMB, upd_be1 + l*EMB,
                                    coef + (st+2)*64, invN);
    k_upd2<<<NODE_GRID, 256, 0, stream>>>(aggr, coef + (st+2)*64, uw2, upd_b2 + l*EMB, partial);
    k_bnfin<<<1, 1024, 0, stream>>>(partial, NODE_GRID, upd_g2 + l*EMB, upd_be2 + l*EMB,
                                    coef + (st+3)*64, invN);
    k_resid<<<ELEM_GRID, 256, 0, stream>>>(h, aggr, coef + (st+3)*64);
  }

  k_pool<<<NB, 256, 0, stream>>>(h, batch, pred_w, pred_b, out);
}